// Round 3
// baseline (5015.474 us; speedup 1.0000x reference)
//
#include <hip/hip_runtime.h>

// MySimpleRNN: h_t = tanh(x_t @ W_xh + h_{t-1} @ W_hh + b_h), return all h_t.
// B=64, T=1024, D=256, U=512, fp32 in/out.
//
// Kernel A: xw = X@W_xh + b (fp32 VALU tiled GEMM) -> staged in d_out.
// Kernel B: recurrence, 64 WGs = 4 groups x 16 col-slices. Round-3: FLAGLESS
//   exchange. Each ring word packs (hi bf16 << 16 | lo bf16), with the lo LSB
//   carrying a step tag ((t>>1)&1)^1 (alternates per slot occupant; rejects
//   0xAA poison whose LSB=0). Consumers spin-validate the payload directly --
//   one L3 round trip instead of ack+flag+read. In-loop barriers are
//   lgkmcnt-only (no vmcnt drain); global stores are never waited on.

typedef __attribute__((ext_vector_type(8))) short short8;
typedef __attribute__((ext_vector_type(4))) float f32x4;
typedef __attribute__((ext_vector_type(4))) unsigned short ushort4v;

#define T_SZ 1024
#define U_SZ 512

// barrier that orders LDS only: no vmcnt(0) drain (unlike __syncthreads)
#define BAR_LGKM() asm volatile("s_waitcnt lgkmcnt(0)\n\ts_barrier" ::: "memory")

__device__ __forceinline__ unsigned short f2bf(float f){
  unsigned u = __float_as_uint(f);
  u += 0x7FFFu + ((u >> 16) & 1u);           // round-to-nearest-even
  return (unsigned short)(u >> 16);
}
__device__ __forceinline__ float bf2f(unsigned short s){
  return __uint_as_float(((unsigned)s) << 16);
}

// ---------------- Kernel A: xw = X @ W_xh + b ----------------
__global__ __launch_bounds__(256) void xw_gemm(const float* __restrict__ X,
                                               const float* __restrict__ W,
                                               const float* __restrict__ bias,
                                               float* __restrict__ out){
  __shared__ float As[16][132];
  __shared__ float Bs[16][68];
  const int tid = threadIdx.x;
  const int tx = tid & 15, ty = tid >> 4;
  const int row0 = blockIdx.x * 128;
  const int col0 = blockIdx.y * 64;
  float acc[8][4];
  #pragma unroll
  for(int a=0;a<8;a++)
    #pragma unroll
    for(int b=0;b<4;b++) acc[a][b]=0.f;

  for(int kc=0;kc<256;kc+=16){
    {
      const int m  = tid >> 2;
      const int kq = (tid & 3) * 4;
      #pragma unroll
      for(int h=0;h<2;h++){
        const float4 v = *(const float4*)&X[(size_t)(row0 + m + 64*h)*256 + kc + kq];
        As[kq+0][m+64*h]=v.x; As[kq+1][m+64*h]=v.y;
        As[kq+2][m+64*h]=v.z; As[kq+3][m+64*h]=v.w;
      }
    }
    {
      const int k = tid >> 4;
      const int c = (tid & 15) * 4;
      *(float4*)&Bs[k][c] = *(const float4*)&W[(size_t)(kc + k)*512 + col0 + c];
    }
    __syncthreads();
    #pragma unroll
    for(int k=0;k<16;k++){
      const float4 b4 = *(const float4*)&Bs[k][tx*4];
      const float4 a0 = *(const float4*)&As[k][ty*8];
      const float4 a1 = *(const float4*)&As[k][ty*8+4];
      const float av[8] = {a0.x,a0.y,a0.z,a0.w,a1.x,a1.y,a1.z,a1.w};
      const float bv[4] = {b4.x,b4.y,b4.z,b4.w};
      #pragma unroll
      for(int ii=0;ii<8;ii++)
        #pragma unroll
        for(int j=0;j<4;j++) acc[ii][j] = fmaf(av[ii], bv[j], acc[ii][j]);
    }
    __syncthreads();
  }
  #pragma unroll
  for(int ii=0;ii<8;ii++){
    const int row = row0 + ty*8 + ii;
    float4 o;
    o.x = acc[ii][0] + bias[col0+tx*4+0];
    o.y = acc[ii][1] + bias[col0+tx*4+1];
    o.z = acc[ii][2] + bias[col0+tx*4+2];
    o.w = acc[ii][3] + bias[col0+tx*4+3];
    *(float4*)&out[(size_t)row*512 + col0 + tx*4] = o;
  }
}

// ---------------- Kernel B: the recurrence ----------------
// grid 64, block 256 (4 waves). g = bid&3 (16-batch group), i = bid>>2 (32-col
// slice). wave w: nt = w&1 (16-col N-tile), kh = w>>1 (K half of 256).
// Ring block (slot, g, p) = 256 qwords; qword u holds values f=2u,2u+1 of the
// flat index f = m*32 + c_local; word = lo | hi<<16, lo LSB = step tag.
__global__ __launch_bounds__(256, 1) void rnn_rec(const float* __restrict__ Whh,
                                                  float* __restrict__ out,
                                                  unsigned long long* __restrict__ ring){
  __shared__ unsigned short Ahi[16][520];
  __shared__ unsigned short Alo[16][520];
  __shared__ float red[2][64][4];

  const int bid = blockIdx.x;
  const int g  = bid & 3;
  const int i  = bid >> 2;
  const int tid = threadIdx.x;
  const int lane = tid & 63;
  const int w  = tid >> 6;
  const int nt = w & 1;
  const int kh = w >> 1;
  const int ln = lane & 15;
  const int lq = lane >> 4;
  const int b0 = g * 16;
  const int c0 = i * 32;
  const int ncol0 = c0 + nt * 16;

  // --- resident W_hh fragments (hi/lo bf16 split) ---
  short8 whi[8], wlo[8];
  #pragma unroll
  for(int kt=0;kt<8;kt++){
    short8 h8, l8;
    const int kb = kh*256 + kt*32 + lq*8;
    #pragma unroll
    for(int j=0;j<8;j++){
      const float wv = Whh[(size_t)(kb+j)*512 + ncol0 + ln];
      const unsigned short hb = f2bf(wv);
      const unsigned short lb = f2bf(wv - bf2f(hb));
      h8[j] = (short)hb; l8[j] = (short)lb;
    }
    whi[kt]=h8; wlo[kt]=l8;
  }
  for(int idx=tid; idx<16*520; idx+=256){
    ((unsigned short*)Ahi)[idx]=0;
    ((unsigned short*)Alo)[idx]=0;
  }
  __syncthreads();

  float xwv[4] = {0.f,0.f,0.f,0.f};
  float hprev[4] = {0.f,0.f,0.f,0.f};
  if(kh==0){
    #pragma unroll
    for(int r=0;r<4;r++)
      xwv[r] = out[((size_t)(b0 + lq*4 + r)*T_SZ + 0)*U_SZ + ncol0 + ln];
  }

  for(int t=0;t<T_SZ;t++){
    if(t>0){
      if(kh==0){  // delayed fp32 h-store for t-1: fire-and-forget (never drained)
        #pragma unroll
        for(int r=0;r<4;r++)
          out[((size_t)(b0 + lq*4 + r)*T_SZ + (t-1))*U_SZ + ncol0 + ln] = hprev[r];
      }
      // --- tag-validated retry read: this wave owns peers p = 4s + w ---
      const unsigned tagb = ((((unsigned)(t-1)) >> 1) & 1u) ^ 1u;
      const unsigned long long* pb[4];
      #pragma unroll
      for(int s=0;s<4;s++){
        const int p = 4*s + w;
        pb[s] = ring + (((size_t)((t-1)&1)*4 + g)*16 + p)*256
                     + (size_t)ln*16 + (size_t)lq*4;
      }
      unsigned long long v[4][4];
      bool ok[4] = {false,false,false,false};
      for(;;){
        #pragma unroll
        for(int s=0;s<4;s++) if(!ok[s]){
          #pragma unroll
          for(int u=0;u<4;u++)
            v[s][u] = __hip_atomic_load(pb[s]+u, __ATOMIC_RELAXED,
                                        __HIP_MEMORY_SCOPE_AGENT);
        }
        #pragma unroll
        for(int s=0;s<4;s++) if(!ok[s]){
          bool o = true;
          #pragma unroll
          for(int u=0;u<4;u++) o = o && ((((unsigned)v[s][u]) & 1u) == tagb);
          ok[s] = o;
        }
        const bool all = ok[0] && ok[1] && ok[2] && ok[3];
        if(__ballot(!all) == 0ull) break;
      }
      #pragma unroll
      for(int s=0;s<4;s++){
        const int p = 4*s + w;
        short8 h8, l8;
        #pragma unroll
        for(int u=0;u<4;u++){
          const unsigned w0 = (unsigned)v[s][u];
          const unsigned w1 = (unsigned)(v[s][u] >> 32);
          l8[2*u]   = (short)(w0 & 0xFFFFu); h8[2*u]   = (short)(w0 >> 16);
          l8[2*u+1] = (short)(w1 & 0xFFFFu); h8[2*u+1] = (short)(w1 >> 16);
        }
        *(short8*)&Ahi[ln][p*32 + lq*8] = h8;
        *(short8*)&Alo[ln][p*32 + lq*8] = l8;
      }
    }
    BAR_LGKM();                             // B1: A (= h_{t-1}) complete

    f32x4 c_hh = {0.f,0.f,0.f,0.f}, c_hl = {0.f,0.f,0.f,0.f}, c_lh = {0.f,0.f,0.f,0.f};
    #pragma unroll
    for(int kt=0;kt<8;kt++){
      const int k = kh*256 + kt*32 + lq*8;
      const short8 ah = *(const short8*)&Ahi[ln][k];
      const short8 al = *(const short8*)&Alo[ln][k];
      c_hh = __builtin_amdgcn_mfma_f32_16x16x32_bf16(ah, whi[kt], c_hh, 0, 0, 0);
      c_hl = __builtin_amdgcn_mfma_f32_16x16x32_bf16(ah, wlo[kt], c_hl, 0, 0, 0);
      c_lh = __builtin_amdgcn_mfma_f32_16x16x32_bf16(al, whi[kt], c_lh, 0, 0, 0);
    }
    f32x4 csum = c_hh + c_hl + c_lh;
    if(kh==1) *(f32x4*)&red[nt][lane][0] = csum;
    BAR_LGKM();                             // B2: partials visible
    if(kh==0){
      const f32x4 o = *(const f32x4*)&red[nt][lane][0];
      csum += o;
      const unsigned mytag = ((((unsigned)t) >> 1) & 1u) ^ 1u;
      #pragma unroll
      for(int r=0;r<4;r++){
        float pre = csum[r] + xwv[r];
        pre = fminf(fmaxf(pre, -12.f), 12.f);
        const float e = __expf(2.f*pre);
        const float h = (e-1.f)/(e+1.f);    // tanh
        hprev[r] = h;
        const unsigned short hb = f2bf(h);
        unsigned short lb = f2bf(h - bf2f(hb));
        lb = (unsigned short)((lb & 0xFFFEu) | mytag);   // embed step tag
        Ahi[lq*4+r][ncol0+ln] = hb;
        Alo[lq*4+r][ncol0+ln] = lb;
      }
      // publish own nt-half: LDS readback -> packed tagged words -> ring
      {
        const int m  = lane >> 2;
        const int q4 = lane & 3;
        const ushort4v hi4 = *(const ushort4v*)&Ahi[m][c0 + nt*16 + q4*4];
        const ushort4v lo4 = *(const ushort4v*)&Alo[m][c0 + nt*16 + q4*4];
        const unsigned w0 = (unsigned)lo4.x | ((unsigned)hi4.x << 16);
        const unsigned w1 = (unsigned)lo4.y | ((unsigned)hi4.y << 16);
        const unsigned w2 = (unsigned)lo4.z | ((unsigned)hi4.z << 16);
        const unsigned w3 = (unsigned)lo4.w | ((unsigned)hi4.w << 16);
        const unsigned long long q0 = (unsigned long long)w0 | ((unsigned long long)w1 << 32);
        const unsigned long long q1 = (unsigned long long)w2 | ((unsigned long long)w3 << 32);
        unsigned long long* dst = ring + (((size_t)(t&1)*4 + g)*16 + i)*256
                                       + (size_t)m*16 + (size_t)nt*8 + (size_t)q4*2;
        __hip_atomic_store(dst+0, q0, __ATOMIC_RELAXED, __HIP_MEMORY_SCOPE_AGENT);
        __hip_atomic_store(dst+1, q1, __ATOMIC_RELAXED, __HIP_MEMORY_SCOPE_AGENT);
      }
      // prefetch xw for t+1 (fire-and-forget; full step to land)
      {
        const int tn = (t < T_SZ-1) ? t+1 : t;
        #pragma unroll
        for(int r=0;r<4;r++)
          xwv[r] = out[((size_t)(b0 + lq*4 + r)*T_SZ + tn)*U_SZ + ncol0 + ln];
      }
    }
  }
  if(kh==0){
    #pragma unroll
    for(int r=0;r<4;r++)
      out[((size_t)(b0 + lq*4 + r)*T_SZ + (T_SZ-1))*U_SZ + ncol0 + ln] = hprev[r];
  }
}

extern "C" void kernel_launch(void* const* d_in, const int* in_sizes, int n_in,
                              void* d_out, int out_size, void* d_ws, size_t ws_size,
                              hipStream_t stream) {
  (void)in_sizes; (void)n_in; (void)out_size; (void)ws_size;
  const float* X   = (const float*)d_in[0];  // [64,1024,256]
  const float* Wxh = (const float*)d_in[1];  // [256,512]
  const float* Whh = (const float*)d_in[2];  // [512,512]
  const float* bh  = (const float*)d_in[3];  // [512]
  float* out = (float*)d_out;                // [64,1024,512]

  unsigned long long* ring = (unsigned long long*)d_ws;  // 256 KB, poison-safe (tag)

  xw_gemm<<<dim3(512, 8), 256, 0, stream>>>(X, Wxh, bh, out);
  rnn_rec<<<64, 256, 0, stream>>>(Whh, out, ring);
}